// Round 1
// baseline (366.682 us; speedup 1.0000x reference)
//
#include <hip/hip_runtime.h>

#define B_  64
#define T_  1024
#define FC_ 256
#define FX_ 512

typedef __bf16 bf16x8 __attribute__((ext_vector_type(8)));
typedef float  f32x4  __attribute__((ext_vector_type(4)));

__device__ inline unsigned short f2bf(float f) {
  union { float f; unsigned int u; } v; v.f = f;
  unsigned int r = v.u + 0x7fffu + ((v.u >> 16) & 1u);  // RNE
  return (unsigned short)(r >> 16);
}

// ---------------------------------------------------------------------------
// Kernel 1: Xt[m, c] = sum_x X[m, x] * W[c, x] + b[c], bf16 output to ws.
// m = b*T + t (same flattening as X). Tiles: BM=128, BN=128 (FC split in 2),
// BK=64. 256 threads = 4 waves (2x2), wave tile 64x64 = 4x4 frags 16x16x32.
// LDS tiles XOR-swizzled: byte ^= (row&7)<<4 (T2) to kill ds_read_b128
// bank conflicts.
// ---------------------------------------------------------------------------
__global__ __launch_bounds__(256, 2)
void k1_xt(const float* __restrict__ X, const float* __restrict__ W,
           const float* __restrict__ bias, unsigned short* __restrict__ Xt)
{
  const int bx   = blockIdx.x;
  const int mt   = bx >> 1;           // 512 m-tiles
  const int nt   = bx & 1;            // 2 n-tiles
  const int tid  = threadIdx.x;
  const int lane = tid & 63;
  const int wid  = tid >> 6;
  const int wm   = wid >> 1, wn = wid & 1;

  __shared__ __align__(16) char sX[128 * 64 * 2];
  __shared__ __align__(16) char sW[128 * 64 * 2];

  f32x4 acc[4][4];
  #pragma unroll
  for (int i = 0; i < 4; ++i)
    #pragma unroll
    for (int j = 0; j < 4; ++j)
      #pragma unroll
      for (int r = 0; r < 4; ++r) acc[i][j][r] = 0.f;

  const int srow = tid >> 4;          // 0..15
  const int scol = (tid & 15) << 2;   // f32 col 0..60

  for (int kc = 0; kc < 8; ++kc) {
    const int k0 = kc * 64;
    float4 xv[8], wv[8];
    #pragma unroll
    for (int p = 0; p < 8; ++p) {
      const int row = p * 16 + srow;
      xv[p] = *(const float4*)(X + (size_t)(mt * 128 + row) * FX_ + k0 + scol);
      wv[p] = *(const float4*)(W + (size_t)(nt * 128 + row) * FX_ + k0 + scol);
    }
    __syncthreads();                  // previous chunk's compute done with LDS
    #pragma unroll
    for (int p = 0; p < 8; ++p) {
      const int row = p * 16 + srow;
      const int off = row * 128 + ((scol * 2) ^ ((row & 7) << 4));
      ushort4 hx, hw;
      hx.x = f2bf(xv[p].x); hx.y = f2bf(xv[p].y); hx.z = f2bf(xv[p].z); hx.w = f2bf(xv[p].w);
      hw.x = f2bf(wv[p].x); hw.y = f2bf(wv[p].y); hw.z = f2bf(wv[p].z); hw.w = f2bf(wv[p].w);
      *(ushort4*)(sX + off) = hx;
      *(ushort4*)(sW + off) = hw;
    }
    __syncthreads();
    #pragma unroll
    for (int kk = 0; kk < 2; ++kk) {
      bf16x8 a[4], b[4];
      const int kb = kk * 64 + ((lane >> 4) << 4);
      #pragma unroll
      for (int i = 0; i < 4; ++i) {
        const int ar = wm * 64 + i * 16 + (lane & 15);
        a[i] = *(const bf16x8*)(sX + ar * 128 + (kb ^ ((ar & 7) << 4)));
        const int br = wn * 64 + i * 16 + (lane & 15);
        b[i] = *(const bf16x8*)(sW + br * 128 + (kb ^ ((br & 7) << 4)));
      }
      #pragma unroll
      for (int i = 0; i < 4; ++i)
        #pragma unroll
        for (int j = 0; j < 4; ++j)
          acc[i][j] = __builtin_amdgcn_mfma_f32_16x16x32_bf16(a[i], b[j], acc[i][j], 0, 0, 0);
    }
  }

  // epilogue: bias + cvt + store bf16 (C/D layout: col=lane&15, row=(lane>>4)*4+reg)
  float bv[4];
  #pragma unroll
  for (int j = 0; j < 4; ++j)
    bv[j] = bias[nt * 128 + wn * 64 + j * 16 + (lane & 15)];
  #pragma unroll
  for (int i = 0; i < 4; ++i) {
    #pragma unroll
    for (int r = 0; r < 4; ++r) {
      const int grow = mt * 128 + wm * 64 + i * 16 + ((lane >> 4) << 2) + r;
      #pragma unroll
      for (int j = 0; j < 4; ++j) {
        const int gcol = nt * 128 + wn * 64 + j * 16 + (lane & 15);
        Xt[(size_t)grow * FC_ + gcol] = f2bf(acc[i][j][r] + bv[j]);
      }
    }
  }
}

// ---------------------------------------------------------------------------
// Kernel 2: one block per t. Z = C_t · Xt_t^T (64x64, K=256) via MFMA,
// fused row-wise logsumexp over j + diag, scaled atomicAdd into out.
// Wave w owns rows 16w..16w+15 (A frag), all 64 cols as 4 B-frags.
// ---------------------------------------------------------------------------
__global__ __launch_bounds__(256, 2)
void k2_loss(const float* __restrict__ C, const unsigned short* __restrict__ Xt,
             float* __restrict__ out)
{
  const int t    = blockIdx.x;
  const int tid  = threadIdx.x;
  const int lane = tid & 63;
  const int wid  = tid >> 6;

  __shared__ __align__(16) char sC [64 * 256 * 2];
  __shared__ __align__(16) char sXt[64 * 256 * 2];

  {
    const int row = tid >> 2;          // 0..63
    const int cg  = tid & 3;
    const float* csrc = C + ((size_t)row * T_ + t) * FC_;
    #pragma unroll
    for (int s = 0; s < 16; ++s) {
      const int col = cg * 4 + s * 16; // f32 elems
      float4 v = *(const float4*)(csrc + col);
      ushort4 h;
      h.x = f2bf(v.x); h.y = f2bf(v.y); h.z = f2bf(v.z); h.w = f2bf(v.w);
      const int off = row * 512 + ((col * 2) ^ ((row & 7) << 4));
      *(ushort4*)(sC + off) = h;
    }
    const unsigned short* xsrc = Xt + ((size_t)row * T_ + t) * FC_;
    #pragma unroll
    for (int s = 0; s < 8; ++s) {
      const int col = cg * 8 + s * 32; // bf16 elems
      uint4 v = *(const uint4*)(xsrc + col);
      const int off = row * 512 + ((col * 2) ^ ((row & 7) << 4));
      *(uint4*)(sXt + off) = v;
    }
  }
  __syncthreads();

  f32x4 acc[4];
  #pragma unroll
  for (int n = 0; n < 4; ++n)
    #pragma unroll
    for (int r = 0; r < 4; ++r) acc[n][r] = 0.f;

  #pragma unroll
  for (int kk = 0; kk < 8; ++kk) {
    const int kb = kk * 64 + ((lane >> 4) << 4);
    const int ar = wid * 16 + (lane & 15);
    bf16x8 a = *(const bf16x8*)(sC + ar * 512 + (kb ^ ((ar & 7) << 4)));
    #pragma unroll
    for (int n = 0; n < 4; ++n) {
      const int br = n * 16 + (lane & 15);
      bf16x8 b = *(const bf16x8*)(sXt + br * 512 + (kb ^ ((br & 7) << 4)));
      acc[n] = __builtin_amdgcn_mfma_f32_16x16x32_bf16(a, b, acc[n], 0, 0, 0);
    }
  }

  // Row-wise lse: row = 16*wid + 4*(lane>>4) + r lives in the 16 lanes sharing
  // lane>>4, spread over the 4 frags (col = 16n + (lane&15)).
  float partial = 0.f;
  #pragma unroll
  for (int r = 0; r < 4; ++r) {
    float m = fmaxf(fmaxf(acc[0][r], acc[1][r]), fmaxf(acc[2][r], acc[3][r]));
    #pragma unroll
    for (int d = 1; d < 16; d <<= 1) m = fmaxf(m, __shfl_xor(m, d));
    float s = __expf(acc[0][r] - m) + __expf(acc[1][r] - m) +
              __expf(acc[2][r] - m) + __expf(acc[3][r] - m);
    #pragma unroll
    for (int d = 1; d < 16; d <<= 1) s += __shfl_xor(s, d);
    const float lse = m + __logf(s);
    // diag: j == i  =>  frag n == wid and (lane&15) == row-in-tile
    float dv = 0.f;
    #pragma unroll
    for (int n = 0; n < 4; ++n) dv = (n == wid) ? acc[n][r] : dv;  // static idx
    const int dl = ((lane >> 4) << 2) + r;
    if ((lane & 15) == dl) partial += dv - lse;
  }
  #pragma unroll
  for (int d = 1; d < 64; d <<= 1) partial += __shfl_xor(partial, d);
  if (lane == 0) atomicAdd(out, partial * (1.0f / (B_ * T_)));
}

extern "C" void kernel_launch(void* const* d_in, const int* in_sizes, int n_in,
                              void* d_out, int out_size, void* d_ws, size_t ws_size,
                              hipStream_t stream) {
  const float* C  = (const float*)d_in[0];
  const float* X  = (const float*)d_in[1];
  const float* W  = (const float*)d_in[2];
  const float* bb = (const float*)d_in[3];
  unsigned short* Xt = (unsigned short*)d_ws;   // 65536*256 bf16 = 32 MB
  float* out = (float*)d_out;

  hipMemsetAsync(out, 0, sizeof(float), stream);
  k1_xt<<<dim3(1024), dim3(256), 0, stream>>>(X, W, bb, Xt);
  k2_loss<<<dim3(1024), dim3(256), 0, stream>>>(C, Xt, out);
}

// Round 2
// 271.509 us; speedup vs baseline: 1.3505x; 1.3505x over previous
//
#include <hip/hip_runtime.h>

#define B_  64
#define T_  1024
#define FC_ 256
#define FX_ 512

typedef __bf16 bf16x8 __attribute__((ext_vector_type(8)));
typedef float  f32x4  __attribute__((ext_vector_type(4)));

__device__ __forceinline__ unsigned short f2bf(float f) {
  union { float f; unsigned int u; } v; v.f = f;
  unsigned int r = v.u + 0x7fffu + ((v.u >> 16) & 1u);  // RNE
  return (unsigned short)(r >> 16);
}
__device__ __forceinline__ unsigned int pk2(float lo, float hi) {
  return (unsigned int)f2bf(lo) | ((unsigned int)f2bf(hi) << 16);
}

// ---------------------------------------------------------------------------
// Prep: W f32 [256][512] -> bf16 (so the fused kernel can global_load_lds it)
// ---------------------------------------------------------------------------
__global__ void k_wcvt(const float* __restrict__ W, unsigned short* __restrict__ Wb) {
  const int i = blockIdx.x * 256 + threadIdx.x;   // 32768 float4-groups
  float4 v = ((const float4*)W)[i];
  ushort4 h;
  h.x = f2bf(v.x); h.y = f2bf(v.y); h.z = f2bf(v.z); h.w = f2bf(v.w);
  ((ushort4*)Wb)[i] = h;
}

// ---------------------------------------------------------------------------
// Fused: block = one t. GEMM1 (Xt_t = X_t * W^T + b, 64x256 K=512) streamed
// over 8 K-chunks (BK=64) with W via async global_load_lds (pre-swizzled
// source, linear LDS dest) and X reg-staged f32->bf16, 2-phase pipelined.
// Then Xt_t -> LDS, C_t (loads issued in prologue, T14) -> LDS,
// GEMM2 (Z = C_t * Xt_t^T, 64x64 K=256) + fused row-lse + diag + atomicAdd.
// LDS union: stage region (80KB) is reused for sC/sXt after GEMM1.
// ---------------------------------------------------------------------------
__global__ __launch_bounds__(512, 2)
void k_fused(const float* __restrict__ C, const float* __restrict__ X,
             const unsigned short* __restrict__ Wb, const float* __restrict__ bias,
             float* __restrict__ out)
{
  __shared__ __align__(16) char sMem[81920];
  char* sX0 = sMem;            // 64 x 128B   (bf16 X chunk, swizzled)
  char* sX1 = sMem + 8192;
  char* sW0 = sMem + 16384;    // 256 x 128B  (bf16 W chunk, swizzled)
  char* sW1 = sMem + 49152;
  char* sC  = sMem;            // 64 x 512B   (bf16 C_t)   -- after GEMM1
  char* sXt = sMem + 32768;    // 64 x 512B   (bf16 Xt_t)  -- after GEMM1

  const int t    = blockIdx.x;
  const int tid  = threadIdx.x;
  const int lane = tid & 63;
  const int wid  = tid >> 6;

  // ---- prologue: issue X chunk0, W chunk0 DMA, then C loads (T14), bias ----
  const int xrow  = tid >> 3;                 // 0..63
  const int xcol  = (tid & 7) * 8;            // f32 col
  const float* xbase = X + ((size_t)xrow * T_ + t) * FX_ + xcol;
  float4 x0a = *(const float4*)(xbase);
  float4 x0b = *(const float4*)(xbase + 4);

  // W chunk DMA: lds dest linear (wave-uniform base + lane*16), source
  // pre-swizzled so LDS content at (c, p) = global (c, p ^ ((c&7)<<4)).
  const int wsw = (((lane & 7) ^ (lane >> 3)) << 4);
  {
    const char* wb0 = (const char*)Wb;        // chunk 0
    #pragma unroll
    for (int l = 0; l < 4; ++l) {
      const int seg = wid * 4 + l;
      const int c   = seg * 8 + (lane >> 3);
      __builtin_amdgcn_global_load_lds(
          (const __attribute__((address_space(1))) unsigned int*)(wb0 + c * 1024 + wsw),
          (__attribute__((address_space(3))) unsigned int*)(sW0 + seg * 1024),
          16, 0, 0);
    }
  }

  const int crow = tid >> 3;                  // 0..63
  const int ccol = (tid & 7) * 32;            // f32 col
  const float* cbase = C + ((size_t)crow * T_ + t) * FC_ + ccol;
  float4 creg[8];
  #pragma unroll
  for (int q = 0; q < 8; ++q) creg[q] = *(const float4*)(cbase + 4 * q);

  const float bv0 = bias[wid * 32 + (lane & 15)];
  const float bv1 = bias[wid * 32 + 16 + (lane & 15)];

  asm volatile("" ::: "memory");              // pin issue order

  // cvt + write X chunk0 (swizzled)
  const int xwoff = xrow * 128 + (((tid & 7) * 16) ^ ((xrow & 7) << 4));
  {
    uint4 pk;
    pk.x = pk2(x0a.x, x0a.y); pk.y = pk2(x0a.z, x0a.w);
    pk.z = pk2(x0b.x, x0b.y); pk.w = pk2(x0b.z, x0b.w);
    *(uint4*)(sX0 + xwoff) = pk;
  }
  __syncthreads();                            // drains W DMA too

  // ---- GEMM1 main loop: wave wid owns Xt cols [32*wid, 32*wid+32) ----
  f32x4 acc[4][2];
  #pragma unroll
  for (int i = 0; i < 4; ++i)
    #pragma unroll
    for (int n2 = 0; n2 < 2; ++n2)
      #pragma unroll
      for (int r = 0; r < 4; ++r) acc[i][n2][r] = 0.f;

  #pragma unroll 2
  for (int k = 0; k < 8; ++k) {
    char* scx = (k & 1) ? sX1 : sX0;
    char* snx = (k & 1) ? sX0 : sX1;
    char* scw = (k & 1) ? sW1 : sW0;
    char* snw = (k & 1) ? sW0 : sW1;

    float4 xn0, xn1;
    if (k < 7) {
      xn0 = *(const float4*)(xbase + (k + 1) * 64);
      xn1 = *(const float4*)(xbase + (k + 1) * 64 + 4);
      const char* wbk = (const char*)Wb + (k + 1) * 128;
      #pragma unroll
      for (int l = 0; l < 4; ++l) {
        const int seg = wid * 4 + l;
        const int c   = seg * 8 + (lane >> 3);
        __builtin_amdgcn_global_load_lds(
            (const __attribute__((address_space(1))) unsigned int*)(wbk + c * 1024 + wsw),
            (__attribute__((address_space(3))) unsigned int*)(snw + seg * 1024),
            16, 0, 0);
      }
    }
    asm volatile("" ::: "memory");

    #pragma unroll
    for (int kk = 0; kk < 2; ++kk) {
      const int kb = kk * 64 + ((lane >> 4) << 4);
      bf16x8 a[4], b2[2];
      #pragma unroll
      for (int i = 0; i < 4; ++i) {
        const int ar = i * 16 + (lane & 15);
        a[i] = *(const bf16x8*)(scx + ar * 128 + (kb ^ ((ar & 7) << 4)));
      }
      #pragma unroll
      for (int n2 = 0; n2 < 2; ++n2) {
        const int br = wid * 32 + n2 * 16 + (lane & 15);
        b2[n2] = *(const bf16x8*)(scw + br * 128 + (kb ^ ((br & 7) << 4)));
      }
      #pragma unroll
      for (int i = 0; i < 4; ++i)
        #pragma unroll
        for (int n2 = 0; n2 < 2; ++n2)
          acc[i][n2] = __builtin_amdgcn_mfma_f32_16x16x32_bf16(a[i], b2[n2], acc[i][n2], 0, 0, 0);
    }

    if (k < 7) {                              // cvt + write next X chunk
      uint4 pk;
      pk.x = pk2(xn0.x, xn0.y); pk.y = pk2(xn0.z, xn0.w);
      pk.z = pk2(xn1.x, xn1.y); pk.w = pk2(xn1.z, xn1.w);
      *(uint4*)(snx + xwoff) = pk;
    }
    __syncthreads();
  }

  // ---- epilogue: Xt (+bias) -> sXt, C regs -> sC (stage region now dead) ----
  #pragma unroll
  for (int i = 0; i < 4; ++i)
    #pragma unroll
    for (int n2 = 0; n2 < 2; ++n2) {
      const int c  = wid * 32 + n2 * 16 + (lane & 15);
      const float bb = (n2 == 0) ? bv0 : bv1;
      #pragma unroll
      for (int r = 0; r < 4; ++r) {
        const int j   = i * 16 + ((lane >> 4) << 2) + r;
        const int off = j * 512 + ((2 * c) ^ ((j & 7) << 4));
        *(unsigned short*)(sXt + off) = f2bf(acc[i][n2][r] + bb);
      }
    }
  #pragma unroll
  for (int q = 0; q < 4; ++q) {
    const int cb  = (tid & 7) * 64 + q * 16;
    const int off = crow * 512 + (cb ^ ((crow & 7) << 4));
    float4 a0 = creg[2 * q], a1 = creg[2 * q + 1];
    uint4 pk;
    pk.x = pk2(a0.x, a0.y); pk.y = pk2(a0.z, a0.w);
    pk.z = pk2(a1.x, a1.y); pk.w = pk2(a1.z, a1.w);
    *(uint4*)(sC + off) = pk;
  }
  __syncthreads();

  // ---- GEMM2 + lse (waves 0..3; proven round-1 code, 512B rows) ----
  if (wid < 4) {
    f32x4 z[4];
    #pragma unroll
    for (int n = 0; n < 4; ++n)
      #pragma unroll
      for (int r = 0; r < 4; ++r) z[n][r] = 0.f;

    #pragma unroll
    for (int kk = 0; kk < 8; ++kk) {
      const int kb = kk * 64 + ((lane >> 4) << 4);
      const int ar = wid * 16 + (lane & 15);
      bf16x8 a = *(const bf16x8*)(sC + ar * 512 + (kb ^ ((ar & 7) << 4)));
      #pragma unroll
      for (int n = 0; n < 4; ++n) {
        const int br = n * 16 + (lane & 15);
        bf16x8 b = *(const bf16x8*)(sXt + br * 512 + (kb ^ ((br & 7) << 4)));
        z[n] = __builtin_amdgcn_mfma_f32_16x16x32_bf16(a, b, z[n], 0, 0, 0);
      }
    }

    float partial = 0.f;
    #pragma unroll
    for (int r = 0; r < 4; ++r) {
      float m = fmaxf(fmaxf(z[0][r], z[1][r]), fmaxf(z[2][r], z[3][r]));
      #pragma unroll
      for (int d = 1; d < 16; d <<= 1) m = fmaxf(m, __shfl_xor(m, d));
      float s = __expf(z[0][r] - m) + __expf(z[1][r] - m) +
                __expf(z[2][r] - m) + __expf(z[3][r] - m);
      #pragma unroll
      for (int d = 1; d < 16; d <<= 1) s += __shfl_xor(s, d);
      const float lse = m + __logf(s);
      float dv = 0.f;
      #pragma unroll
      for (int n = 0; n < 4; ++n) dv = (n == wid) ? z[n][r] : dv;
      const int dl = ((lane >> 4) << 2) + r;
      if ((lane & 15) == dl) partial += dv - lse;
    }
    #pragma unroll
    for (int d = 1; d < 64; d <<= 1) partial += __shfl_xor(partial, d);
    if (lane == 0) atomicAdd(out, partial * (1.0f / (B_ * T_)));
  }
}

extern "C" void kernel_launch(void* const* d_in, const int* in_sizes, int n_in,
                              void* d_out, int out_size, void* d_ws, size_t ws_size,
                              hipStream_t stream) {
  const float* C  = (const float*)d_in[0];
  const float* X  = (const float*)d_in[1];
  const float* W  = (const float*)d_in[2];
  const float* bb = (const float*)d_in[3];
  unsigned short* Wb = (unsigned short*)d_ws;   // 256KB bf16 W
  float* out = (float*)d_out;

  hipMemsetAsync(out, 0, sizeof(float), stream);
  k_wcvt <<<dim3(128),  dim3(256), 0, stream>>>(W, Wb);
  k_fused<<<dim3(1024), dim3(512), 0, stream>>>(C, X, Wb, bb, out);
}